// Round 6
// baseline (335.719 us; speedup 1.0000x reference)
//
#include <hip/hip_runtime.h>
#include <hip/hip_bf16.h>

#define N_NODES 2048
#define L_SEQ   100
#define ROWS    (N_NODES * L_SEQ)   // 204800
#define HEADS   4
#define GHID    64

typedef __attribute__((ext_vector_type(8))) short bf16x8;
typedef __attribute__((ext_vector_type(4))) float floatx4;

// round-half-up bf16 cvt: 2 VALU (add, shift). <=1 ulp diff vs RNE (ties only).
__device__ __forceinline__ short f2bf(float f) {
    union { float f; unsigned u; } v; v.f = f;
    return (short)((v.u + 0x8000u) >> 16);
}

// ---------------- workspace layout (float offsets) ----------------
constexpr size_t OFF_WCOMB = 0;                           // 16*128
constexpr size_t OFF_BCOMB = 2048;                        // 128
constexpr size_t OFF_AEXP  = 2176;                        // 16
constexpr size_t OFF_WIGS  = 2192;                        // 65536 bf16 (32768 f)
constexpr size_t OFF_WBS   = 34960;                       // 4096 bf16 (2048 f)
constexpr size_t OFF_WCS   = 37008;                       // 2048 bf16 (1024 f)
constexpr size_t OFF_BM    = 38032;                       // ROWS*16
constexpr size_t OFF_CM    = OFF_BM + (size_t)ROWS * 16;  // ROWS*16 (end 26.4 MB)
constexpr size_t OFF_GAT_BIG = OFF_CM + (size_t)ROWS * 16; // non-aliased GAT (if ws allows)

// GAT scratch offsets relative to a base pointer (aliased onto BM, or at OFF_GAT_BIG)
constexpr size_t GXT1 = 0;                                   // 4*2048*64
constexpr size_t GES1 = (size_t)HEADS * N_NODES * GHID;      // 524288
constexpr size_t GED1 = GES1 + (size_t)HEADS * N_NODES;      // +8192
constexpr size_t GXT2 = GED1 + (size_t)HEADS * N_NODES;      // +8192
constexpr size_t GES2 = GXT2 + (size_t)N_NODES * GHID;       // +131072
constexpr size_t GED2 = GES2 + N_NODES;
constexpr size_t GCNT = GED2 + N_NODES;                      // CSR counts (int)
constexpr size_t GLIST = GCNT + N_NODES;                     // CSR lists, stride 128 (int)
constexpr size_t GAT_TOTAL = GLIST + (size_t)N_NODES * 128;  // ~940k floats

// ---------------- kA: fused weight prep (unchanged, verified) ----------------
__global__ __launch_bounds__(256) void kA_prep(
    const float* __restrict__ Wo, const float* __restrict__ bo,
    const float* __restrict__ Wfc, const float* __restrict__ bfc,
    const float* __restrict__ A_log,
    const float* __restrict__ Wi, const float* __restrict__ Wg,
    const float* __restrict__ Wb, const float* __restrict__ Wc,
    float* __restrict__ ws) {
    const int b = blockIdx.x;
    if (b < 9) {
        int i = b * 256 + threadIdx.x;
        if (i < 2048) {
            int row = i >> 7, col = i & 127;
            float a = 0.f;
            for (int f = 0; f < 128; f++) a += Wo[row * 128 + f] * Wfc[f * 128 + col];
            ws[OFF_WCOMB + i] = a;
        } else if (i < 2176) {
            int col = i - 2048;
            float acc = bfc[col];
            for (int f = 0; f < 128; f++) acc += bo[f] * Wfc[f * 128 + col];
            ws[OFF_BCOMB + col] = acc;
        } else if (i < 2192) {
            int s = i - 2176;
            ws[OFF_AEXP + s] = expf(0.01f * expf(A_log[s]));
        }
        return;
    }
    int i = (b - 9) * 256 + threadIdx.x;
    short* wigs = (short*)(ws + OFF_WIGS);
    short* wbs  = (short*)(ws + OFF_WBS);
    short* wcs  = (short*)(ws + OFF_WCS);
    if (i < 65536) {
        int j = i & 7, lane = (i >> 3) & 63, ks = (i >> 9) & 3, nt = i >> 11;
        int w = nt >> 3, t = nt & 7;
        int col = w * 64 + (t & 3) * 16 + (lane & 15);
        int k   = ks * 32 + (lane >> 4) * 8 + j;
        float v = (t < 4) ? Wi[k * 256 + col] : Wg[k * 256 + col];
        wigs[i] = f2bf(v);
    } else if (i < 65536 + 4096) {
        int ii = i - 65536;
        int j = ii & 7, lane = (ii >> 3) & 63, ks = ii >> 9;
        int k = ks * 32 + (lane >> 4) * 8 + j, n = lane & 15;
        wbs[ii] = f2bf(Wb[k * 16 + n]);
    } else if (i < 65536 + 4096 + 2048) {
        int ii = i - 65536 - 4096;
        int j = ii & 7, lane = (ii >> 3) & 63, ks = ii >> 9;
        int k = ks * 32 + (lane >> 4) * 8 + j, n = lane & 15;
        wcs[ii] = f2bf(Wc[k * 16 + n]);
    }
}

// ---------------- K1: MFMA gated GEMM + gating + B/C GEMMs ----------------
// v4: padded LDS restored (v2, proven; swizzle was -5us VALU, conflicts are
// structural b128 phases: 176 reads x 4 = 704/block, layout-independent).
// launch_bounds (512,3): arch-VGPR cap 64 -> ~106 so bfr double-buffer fits;
// prefetch ks+1's Wigs fragments during ks's MFMAs (kills the ~200cy L2
// load-use chain that 64 regs forced). afr narrowed to per-mt (8 regs live).
__global__ __launch_bounds__(512, 3) void k1_mfma(
    const float* __restrict__ temporal, const float* __restrict__ pos,
    const float* __restrict__ bi, const float* __restrict__ bg,
    const float* __restrict__ bb, const float* __restrict__ bc,
    const float* __restrict__ ws, float* __restrict__ Bm, float* __restrict__ Cm) {
    __shared__ short xbf[64][136];   // +8 pad
    __shared__ short gbf[64][264];   // +8 pad
    const int tid = threadIdx.x, wave = tid >> 6, lane = tid & 63;
    const int m = lane & 15, quad = lane >> 4;
    const int r0 = blockIdx.x * 64;
    const int l0 = r0 % L_SEQ;

    // stage x = temporal + pos -> bf16 LDS
#pragma unroll
    for (int i = 0; i < 4; i++) {
        int f4  = i * 512 + tid;
        int row = f4 >> 5;
        int c4  = (f4 & 31) * 4;
        int l = l0 + row; if (l >= L_SEQ) l -= L_SEQ;
        float4 tv = *(const float4*)(temporal + (size_t)(r0 + row) * 128 + c4);
        float4 pv = *(const float4*)(pos + l * 128 + c4);
        short4 sv;
        sv.x = f2bf(tv.x + pv.x); sv.y = f2bf(tv.y + pv.y);
        sv.z = f2bf(tv.z + pv.z); sv.w = f2bf(tv.w + pv.w);
        *(short4*)&xbf[row][c4] = sv;
    }
    __syncthreads();

    // main gated GEMM: per wave 4 M-tiles x (2 I-tiles + 2 G-tiles), K=128
    const short* Wigs = (const short*)(ws + OFF_WIGS);
    const int wg = wave >> 1, wp = wave & 1;
    const short* bptr[4];
#pragma unroll
    for (int jl = 0; jl < 4; jl++) {
        int ntg = wg * 8 + wp * 2 + (jl & 1) + ((jl >> 1) << 2);
        bptr[jl] = Wigs + (size_t)(ntg * 4 * 64 + lane) * 8;   // ks stride = 512 shorts
    }
    floatx4 acc[4][4] = {};
    bf16x8 bcur[4], bnxt[4];
#pragma unroll
    for (int jl = 0; jl < 4; jl++) bcur[jl] = *(const bf16x8*)(bptr[jl]);
#pragma unroll
    for (int ks = 0; ks < 4; ks++) {
        if (ks < 3) {
#pragma unroll
            for (int jl = 0; jl < 4; jl++)
                bnxt[jl] = *(const bf16x8*)(bptr[jl] + (ks + 1) * 512);
        }
#pragma unroll
        for (int mt = 0; mt < 4; mt++) {
            bf16x8 afr = *(const bf16x8*)&xbf[mt * 16 + m][ks * 32 + quad * 8];
#pragma unroll
            for (int jl = 0; jl < 4; jl++)
                acc[mt][jl] = __builtin_amdgcn_mfma_f32_16x16x32_bf16(
                    afr, bcur[jl], acc[mt][jl], 0, 0, 0);
        }
        if (ks < 3) {
#pragma unroll
            for (int jl = 0; jl < 4; jl++) bcur[jl] = bnxt[jl];
        }
    }

    // gating: gated = (I+bi)*sigmoid(G+bg)
    const float NL2E = -1.44269504f;
#pragma unroll
    for (int tp = 0; tp < 2; tp++) {
        int col = wave * 32 + tp * 16 + m;
        float biv = bi[col];
        float bgs = bg[col] * NL2E;
#pragma unroll
        for (int mt = 0; mt < 4; mt++) {
#pragma unroll
            for (int r = 0; r < 4; r++) {
                float li = acc[mt][tp][r] + biv;
                float ex = __builtin_amdgcn_exp2f(fmaf(acc[mt][tp + 2][r], NL2E, bgs));
                float g  = li * __builtin_amdgcn_rcpf(1.f + ex);
                gbf[mt * 16 + quad * 4 + r][col] = f2bf(g);
            }
        }
    }
    __syncthreads();

    // Tail split: waves 0-3: B = gated@Wb + bb (K=256); waves 4-7: C = x@Wc + bc (K=128)
    if (wave < 4) {
        const short* Wbs = (const short*)(ws + OFF_WBS);
        floatx4 accB = {};
#pragma unroll
        for (int ks = 0; ks < 8; ks++) {
            bf16x8 a = *(const bf16x8*)&gbf[wave * 16 + m][ks * 32 + quad * 8];
            bf16x8 b = *(const bf16x8*)(Wbs + (size_t)(ks * 64 + lane) * 8);
            accB = __builtin_amdgcn_mfma_f32_16x16x32_bf16(a, b, accB, 0, 0, 0);
        }
        float bbv = bb[m];
#pragma unroll
        for (int r = 0; r < 4; r++) {
            int row = r0 + wave * 16 + quad * 4 + r;
            Bm[(size_t)row * 16 + m] = accB[r] + bbv;
        }
    } else {
        const short* Wcs = (const short*)(ws + OFF_WCS);
        const int mt = wave - 4;
        floatx4 accC = {};
#pragma unroll
        for (int ks = 0; ks < 4; ks++) {
            bf16x8 a = *(const bf16x8*)&xbf[mt * 16 + m][ks * 32 + quad * 8];
            bf16x8 b = *(const bf16x8*)(Wcs + (size_t)(ks * 64 + lane) * 8);
            accC = __builtin_amdgcn_mfma_f32_16x16x32_bf16(a, b, accC, 0, 0, 0);
        }
        float bcv = bc[m];
#pragma unroll
        for (int r = 0; r < 4; r++) {
            int row = r0 + mt * 16 + quad * 4 + r;
            Cm[(size_t)row * 16 + m] = accC[r] + bcv;
        }
    }
}

// ---------------- scan body (2 nodes / 256-thr block) ----------------
struct __align__(16) ScanSmem { float sb[2][1600]; float sc[2][1600]; };

__device__ __forceinline__ void scan_body(const float* __restrict__ ws,
                                          float* __restrict__ out,
                                          ScanSmem& sm, int bid) {
    const int tid = threadIdx.x;
    const int sub = tid >> 7, t = tid & 127;
    const int n = bid * 2 + sub;
    float* sbp = sm.sb[sub];
    float* scp = sm.sc[sub];
    const float4* Bm4 = (const float4*)(ws + OFF_BM + (size_t)n * 1600);
    const float4* Cm4 = (const float4*)(ws + OFF_CM + (size_t)n * 1600);
#pragma unroll
    for (int i = 0; i < 4; i++) {
        int idx = i * 128 + t;
        if (idx < 400) {
            ((float4*)sbp)[idx] = Bm4[idx];
            ((float4*)scp)[idx] = Cm4[idx];
        }
    }
    float w[16];
#pragma unroll
    for (int s = 0; s < 16; s++) w[s] = ws[OFF_WCOMB + s * 128 + t];
    const float bcb = ws[OFF_BCOMB + t];
    __syncthreads();
    if (t < 16) {
        const int s = t;
        const float As = ws[OFF_AEXP + s];
        float h = 0.f;
#pragma unroll
        for (int lc = 0; lc < 5; lc++) {
            float lb[20], lv[20];
#pragma unroll
            for (int q = 0; q < 20; q++) {
                lb[q] = sbp[(lc * 20 + q) * 16 + s];
                lv[q] = scp[(lc * 20 + q) * 16 + s];
            }
#pragma unroll
            for (int q = 0; q < 20; q++) {
                h = fmaf(As, h, lb[q]);
                sbp[(lc * 20 + q) * 16 + s] = h * lv[q];   // ys in-place
            }
        }
    }
    __syncthreads();
    float* op = out + (size_t)n * L_SEQ * 128 + t;
#pragma unroll 2
    for (int l = 0; l < L_SEQ; l++) {
        const float4 y0 = *(const float4*)(sbp + l * 16 + 0);
        const float4 y1 = *(const float4*)(sbp + l * 16 + 4);
        const float4 y2 = *(const float4*)(sbp + l * 16 + 8);
        const float4 y3 = *(const float4*)(sbp + l * 16 + 12);
        float a0 = fmaf(y0.x, w[0], bcb);
        float a1 = y0.y * w[1];
        float a2 = y0.z * w[2];
        float a3 = y0.w * w[3];
        a0 = fmaf(y1.x, w[4], a0); a1 = fmaf(y1.y, w[5], a1);
        a2 = fmaf(y1.z, w[6], a2); a3 = fmaf(y1.w, w[7], a3);
        a0 = fmaf(y2.x, w[8], a0); a1 = fmaf(y2.y, w[9], a1);
        a2 = fmaf(y2.z, w[10], a2); a3 = fmaf(y2.w, w[11], a3);
        a0 = fmaf(y3.x, w[12], a0); a1 = fmaf(y3.y, w[13], a1);
        a2 = fmaf(y3.z, w[14], a2); a3 = fmaf(y3.w, w[15], a3);
        op[(size_t)l * 128] = (a0 + a1) + (a2 + a3);
    }
}

// ---------------- xt1 body (1 node / 256-thr block) ----------------
__device__ __forceinline__ void xt1_body(const float* __restrict__ gx,
                                         const float* __restrict__ W1,
                                         const float* __restrict__ a1,
                                         float* __restrict__ gat, int n) {
    const int tid = threadIdx.x;
    const int h = tid >> 6, o = tid & 63;
    float acc = 0.f;
    for (int f = 0; f < 128; f++)
        acc += gx[n * 128 + f] * W1[(h * 128 + f) * 64 + o];
    gat[GXT1 + ((size_t)h * 2048 + n) * 64 + o] = acc;
    float es = acc * a1[h * 128 + o];
    float ed = acc * a1[h * 128 + 64 + o];
#pragma unroll
    for (int off = 32; off > 0; off >>= 1) {
        es += __shfl_down(es, off);
        ed += __shfl_down(ed, off);
    }
    if (o == 0) { gat[GES1 + h * 2048 + n] = es; gat[GED1 + h * 2048 + n] = ed; }
}

__global__ __launch_bounds__(256) void k2_scan(const float* __restrict__ ws,
                                               float* __restrict__ out) {
    __shared__ ScanSmem sm;
    scan_body(ws, out, sm, blockIdx.x);
}

__global__ __launch_bounds__(256) void k4_xt1(const float* __restrict__ gx,
                                              const float* __restrict__ W1,
                                              const float* __restrict__ a1,
                                              float* __restrict__ gat) {
    xt1_body(gx, W1, a1, gat, blockIdx.x);
}

// fused scan + xt1 (only when GAT scratch does NOT alias BM)
__global__ __launch_bounds__(256) void k24_fused(
    const float* __restrict__ ws, float* __restrict__ out,
    const float* __restrict__ gx, const float* __restrict__ W1,
    const float* __restrict__ a1, float* __restrict__ gat) {
    __shared__ ScanSmem sm;
    if (blockIdx.x < N_NODES / 2) scan_body(ws, out, sm, blockIdx.x);
    else                          xt1_body(gx, W1, a1, gat, blockIdx.x - N_NODES / 2);
}

// ---------------- K56: att1 + relu + fused h1@W2 + es2/ed2 + CSR persist ----------------
__global__ __launch_bounds__(256) void k56_att1(const float* __restrict__ adj,
                                                const float* __restrict__ W2,
                                                const float* __restrict__ a2,
                                                float* __restrict__ gat) {
    __shared__ int list[192];
    __shared__ int seg[4][64];
    __shared__ int scnt[4];
    __shared__ float sh1[256];
    __shared__ float sred[4][64];
    const int n = blockIdx.x, tid = threadIdx.x;
    const int h = tid >> 6, o = tid & 63;   // h doubles as wave index
    // ballot-ordered scan: wave h covers j in [512h, 512h+512)
    {
        int c = 0;
#pragma unroll
        for (int ch = 0; ch < 8; ch++) {
            int j = h * 512 + ch * 64 + o;
            unsigned long long mask = __ballot(adj[(size_t)n * 2048 + j] > 0.f);
            int pos = c + __popcll(mask & ((1ull << o) - 1ull));
            if ((mask >> o) & 1ull) { if (pos < 64) seg[h][pos] = j; }
            c += (int)__popcll(mask);
        }
        if (o == 0) scnt[h] = (c < 64) ? c : 64;
    }
    __syncthreads();
    const int c0 = scnt[0], c1 = scnt[1], c2 = scnt[2], c3 = scnt[3];
    const int offw = (h > 0 ? c0 : 0) + (h > 1 ? c1 : 0) + (h > 2 ? c2 : 0);
    const int cnt = c0 + c1 + c2 + c3;
    if (o < scnt[h]) list[offw + o] = seg[h][o];
    __syncthreads();
    // persist CSR for k7
    {
        int* gcnt  = (int*)(gat + GCNT);
        int* glist = (int*)(gat + GLIST);
        if (tid == 0) gcnt[n] = (cnt < 128) ? cnt : 128;
        if (tid < cnt && tid < 128) glist[(size_t)n * 128 + tid] = list[tid];
    }
    // layer-1 attention
    {
        const float  es = gat[GES1 + h * 2048 + n];
        const float* ed = gat + GED1 + h * 2048;
        const float* xt = gat + GXT1 + (size_t)h * 2048 * 64;
        float num = 0.f, den = 0.f;
        for (int ii = 0; ii < cnt; ii++) {
            int j = list[ii];
            float e = es + ed[j];
            e = (e > 0.f) ? e : 0.2f * e;
            float wgt = expf(e);
            den += wgt;
            num += wgt * xt[(size_t)j * 64 + o];
        }
        float v = num / den;
        sh1[h * 64 + o] = v > 0.f ? v : 0.f;
    }
    __syncthreads();
    {
        float part = 0.f;
        const int f0 = h * 64;
#pragma unroll 8
        for (int f = 0; f < 64; f++)
            part += sh1[f0 + f] * W2[(f0 + f) * 64 + o];
        sred[h][o] = part;
    }
    __syncthreads();
    if (tid < 64) {
        float xt2v = sred[0][tid] + sred[1][tid] + sred[2][tid] + sred[3][tid];
        gat[GXT2 + (size_t)n * 64 + tid] = xt2v;
        float es = xt2v * a2[tid];
        float ed = xt2v * a2[64 + tid];
#pragma unroll
        for (int off = 32; off > 0; off >>= 1) {
            es += __shfl_down(es, off);
            ed += __shfl_down(ed, off);
        }
        if (tid == 0) { gat[GES2 + n] = es; gat[GED2 + n] = ed; }
    }
}

// ---------------- K7: layer-2 attention -> gat out (consumes CSR) ----------------
__global__ __launch_bounds__(256) void k7_att2(const float* __restrict__ gat,
                                               float* __restrict__ gout) {
    __shared__ int list[128];
    __shared__ float snum[4][64];
    __shared__ float sden[4];
    const int n = blockIdx.x, tid = threadIdx.x;
    const int g = tid >> 6, o = tid & 63;
    const int* gcnt  = (const int*)(gat + GCNT);
    const int* glist = (const int*)(gat + GLIST);
    const int mm = gcnt[n];
    if (tid < mm) list[tid] = glist[(size_t)n * 128 + tid];
    __syncthreads();
    const float es = gat[GES2 + n];
    float num = 0.f, den = 0.f;
    for (int ii = g; ii < mm; ii += 4) {
        int j = list[ii];
        float e = es + gat[GED2 + j];
        e = (e > 0.f) ? e : 0.2f * e;
        float wgt = expf(e);
        den += wgt;
        num += wgt * gat[GXT2 + (size_t)j * 64 + o];
    }
    snum[g][o] = num;
    if (o == 0) sden[g] = den;
    __syncthreads();
    if (tid < 64) {
        float nt = snum[0][tid] + snum[1][tid] + snum[2][tid] + snum[3][tid];
        float dt = sden[0] + sden[1] + sden[2] + sden[3];
        gout[(size_t)n * 64 + tid] = nt / dt;
    }
}

extern "C" void kernel_launch(void* const* d_in, const int* in_sizes, int n_in,
                              void* d_out, int out_size, void* d_ws, size_t ws_size,
                              hipStream_t stream) {
    const float* temporal = (const float*)d_in[0];
    const float* graph_x  = (const float*)d_in[1];
    const float* adj      = (const float*)d_in[2];
    const float* pos      = (const float*)d_in[3];
    const float* Wi  = (const float*)d_in[4];
    const float* bi  = (const float*)d_in[5];
    const float* Wg  = (const float*)d_in[6];
    const float* bg  = (const float*)d_in[7];
    const float* A_log = (const float*)d_in[8];
    const float* Wb  = (const float*)d_in[9];
    const float* bb  = (const float*)d_in[10];
    const float* Wc  = (const float*)d_in[11];
    const float* bc  = (const float*)d_in[12];
    const float* Wo  = (const float*)d_in[13];
    const float* bo  = (const float*)d_in[14];
    const float* Wfc = (const float*)d_in[15];
    const float* bfc = (const float*)d_in[16];
    const float* W1  = (const float*)d_in[17];
    const float* a1  = (const float*)d_in[18];
    const float* W2  = (const float*)d_in[19];
    const float* a2  = (const float*)d_in[20];

    float* ws = (float*)d_ws;
    float* out_mamba = (float*)d_out;
    float* out_gat   = out_mamba + (size_t)ROWS * 128;

    const bool big_ws = ws_size >= (OFF_GAT_BIG + GAT_TOTAL) * sizeof(float);
    float* gat = big_ws ? (ws + OFF_GAT_BIG) : (ws + OFF_BM);   // alias BM if tight

    kA_prep<<<289, 256, 0, stream>>>(Wo, bo, Wfc, bfc, A_log, Wi, Wg, Wb, Wc, ws);
    k1_mfma<<<ROWS / 64, 512, 0, stream>>>(temporal, pos, bi, bg, bb, bc, ws,
                                           ws + OFF_BM, ws + OFF_CM);
    if (big_ws) {
        k24_fused<<<N_NODES / 2 + N_NODES, 256, 0, stream>>>(ws, out_mamba,
                                                             graph_x, W1, a1, gat);
    } else {
        k2_scan<<<N_NODES / 2, 256, 0, stream>>>(ws, out_mamba);
        k4_xt1<<<N_NODES, 256, 0, stream>>>(graph_x, W1, a1, gat);
    }
    k56_att1<<<N_NODES, 256, 0, stream>>>(adj, W2, a2, gat);
    k7_att2<<<N_NODES, 256, 0, stream>>>(gat, out_gat);
}

// Round 7
// 329.144 us; speedup vs baseline: 1.0200x; 1.0200x over previous
//
#include <hip/hip_runtime.h>
#include <hip/hip_bf16.h>

#define N_NODES 2048
#define L_SEQ   100
#define ROWS    (N_NODES * L_SEQ)   // 204800
#define HEADS   4
#define GHID    64

typedef __attribute__((ext_vector_type(8))) short bf16x8;
typedef __attribute__((ext_vector_type(4))) float floatx4;

// round-half-up bf16 cvt: 2 VALU (add, shift). <=1 ulp diff vs RNE (ties only).
__device__ __forceinline__ short f2bf(float f) {
    union { float f; unsigned u; } v; v.f = f;
    return (short)((v.u + 0x8000u) >> 16);
}

// ---------------- workspace layout (float offsets) ----------------
constexpr size_t OFF_WCOMB = 0;                           // 16*128
constexpr size_t OFF_BCOMB = 2048;                        // 128
constexpr size_t OFF_AEXP  = 2176;                        // 16
constexpr size_t OFF_WIGS  = 2192;                        // 65536 bf16 (32768 f)
constexpr size_t OFF_WBS   = 34960;                       // 4096 bf16 (2048 f)
constexpr size_t OFF_WCS   = 37008;                       // 2048 bf16 (1024 f)
constexpr size_t OFF_BM    = 38032;                       // ROWS*16
constexpr size_t OFF_CM    = OFF_BM + (size_t)ROWS * 16;  // ROWS*16 (end 26.4 MB)
constexpr size_t OFF_GAT_BIG = OFF_CM + (size_t)ROWS * 16; // non-aliased GAT (if ws allows)

// GAT scratch offsets relative to a base pointer (aliased onto BM, or at OFF_GAT_BIG)
constexpr size_t GXT1 = 0;                                   // 4*2048*64
constexpr size_t GES1 = (size_t)HEADS * N_NODES * GHID;      // 524288
constexpr size_t GED1 = GES1 + (size_t)HEADS * N_NODES;      // +8192
constexpr size_t GXT2 = GED1 + (size_t)HEADS * N_NODES;      // +8192
constexpr size_t GES2 = GXT2 + (size_t)N_NODES * GHID;       // +131072
constexpr size_t GED2 = GES2 + N_NODES;
constexpr size_t GCNT = GED2 + N_NODES;                      // CSR counts (int)
constexpr size_t GLIST = GCNT + N_NODES;                     // CSR lists, stride 128 (int)
constexpr size_t GAT_TOTAL = GLIST + (size_t)N_NODES * 128;  // ~940k floats

// ---------------- kA: fused weight prep (unchanged, verified) ----------------
__global__ __launch_bounds__(256) void kA_prep(
    const float* __restrict__ Wo, const float* __restrict__ bo,
    const float* __restrict__ Wfc, const float* __restrict__ bfc,
    const float* __restrict__ A_log,
    const float* __restrict__ Wi, const float* __restrict__ Wg,
    const float* __restrict__ Wb, const float* __restrict__ Wc,
    float* __restrict__ ws) {
    const int b = blockIdx.x;
    if (b < 9) {
        int i = b * 256 + threadIdx.x;
        if (i < 2048) {
            int row = i >> 7, col = i & 127;
            float a = 0.f;
            for (int f = 0; f < 128; f++) a += Wo[row * 128 + f] * Wfc[f * 128 + col];
            ws[OFF_WCOMB + i] = a;
        } else if (i < 2176) {
            int col = i - 2048;
            float acc = bfc[col];
            for (int f = 0; f < 128; f++) acc += bo[f] * Wfc[f * 128 + col];
            ws[OFF_BCOMB + col] = acc;
        } else if (i < 2192) {
            int s = i - 2176;
            ws[OFF_AEXP + s] = expf(0.01f * expf(A_log[s]));
        }
        return;
    }
    int i = (b - 9) * 256 + threadIdx.x;
    short* wigs = (short*)(ws + OFF_WIGS);
    short* wbs  = (short*)(ws + OFF_WBS);
    short* wcs  = (short*)(ws + OFF_WCS);
    if (i < 65536) {
        int j = i & 7, lane = (i >> 3) & 63, ks = (i >> 9) & 3, nt = i >> 11;
        int w = nt >> 3, t = nt & 7;
        int col = w * 64 + (t & 3) * 16 + (lane & 15);
        int k   = ks * 32 + (lane >> 4) * 8 + j;
        float v = (t < 4) ? Wi[k * 256 + col] : Wg[k * 256 + col];
        wigs[i] = f2bf(v);
    } else if (i < 65536 + 4096) {
        int ii = i - 65536;
        int j = ii & 7, lane = (ii >> 3) & 63, ks = ii >> 9;
        int k = ks * 32 + (lane >> 4) * 8 + j, n = lane & 15;
        wbs[ii] = f2bf(Wb[k * 16 + n]);
    } else if (i < 65536 + 4096 + 2048) {
        int ii = i - 65536 - 4096;
        int j = ii & 7, lane = (ii >> 3) & 63, ks = ii >> 9;
        int k = ks * 32 + (lane >> 4) * 8 + j, n = lane & 15;
        wcs[ii] = f2bf(Wc[k * 16 + n]);
    }
}

// ---------------- k1 body: proven v2 (75 us, (512,4), padded LDS) ----------------
__device__ __forceinline__ void k1_body(
    const float* __restrict__ temporal, const float* __restrict__ pos,
    const float* __restrict__ bi, const float* __restrict__ bg,
    const float* __restrict__ bb, const float* __restrict__ bc,
    const float* __restrict__ ws, float* __restrict__ Bm, float* __restrict__ Cm,
    short (*xbf)[136], short (*gbf)[264], int bid) {
    const int tid = threadIdx.x, wave = tid >> 6, lane = tid & 63;
    const int m = lane & 15, quad = lane >> 4;
    const int r0 = bid * 64;
    const int l0 = r0 % L_SEQ;

    // stage x = temporal + pos -> bf16 LDS
#pragma unroll
    for (int i = 0; i < 4; i++) {
        int f4  = i * 512 + tid;
        int row = f4 >> 5;
        int c4  = (f4 & 31) * 4;
        int l = l0 + row; if (l >= L_SEQ) l -= L_SEQ;
        float4 tv = *(const float4*)(temporal + (size_t)(r0 + row) * 128 + c4);
        float4 pv = *(const float4*)(pos + l * 128 + c4);
        short4 sv;
        sv.x = f2bf(tv.x + pv.x); sv.y = f2bf(tv.y + pv.y);
        sv.z = f2bf(tv.z + pv.z); sv.w = f2bf(tv.w + pv.w);
        *(short4*)&xbf[row][c4] = sv;
    }
    __syncthreads();

    // main gated GEMM: per wave 4 M-tiles x (2 I-tiles + 2 G-tiles), K=128
    const short* Wigs = (const short*)(ws + OFF_WIGS);
    const int wg = wave >> 1, wp = wave & 1;
    floatx4 acc[4][4] = {};
#pragma unroll
    for (int ks = 0; ks < 4; ks++) {
        bf16x8 bfr[4];
#pragma unroll
        for (int jl = 0; jl < 4; jl++) {
            int ntg = wg * 8 + wp * 2 + (jl & 1) + ((jl >> 1) << 2);
            bfr[jl] = *(const bf16x8*)(Wigs + (size_t)((ntg * 4 + ks) * 64 + lane) * 8);
        }
        bf16x8 afr[4];
#pragma unroll
        for (int mt = 0; mt < 4; mt++)
            afr[mt] = *(const bf16x8*)&xbf[mt * 16 + m][ks * 32 + quad * 8];
#pragma unroll
        for (int mt = 0; mt < 4; mt++)
#pragma unroll
            for (int jl = 0; jl < 4; jl++)
                acc[mt][jl] = __builtin_amdgcn_mfma_f32_16x16x32_bf16(
                    afr[mt], bfr[jl], acc[mt][jl], 0, 0, 0);
    }

    // gating: gated = (I+bi)*sigmoid(G+bg)
    const float NL2E = -1.44269504f;
#pragma unroll
    for (int tp = 0; tp < 2; tp++) {
        int col = wave * 32 + tp * 16 + m;
        float biv = bi[col];
        float bgs = bg[col] * NL2E;
#pragma unroll
        for (int mt = 0; mt < 4; mt++) {
#pragma unroll
            for (int r = 0; r < 4; r++) {
                float li = acc[mt][tp][r] + biv;
                float ex = __builtin_amdgcn_exp2f(fmaf(acc[mt][tp + 2][r], NL2E, bgs));
                float g  = li * __builtin_amdgcn_rcpf(1.f + ex);
                gbf[mt * 16 + quad * 4 + r][col] = f2bf(g);
            }
        }
    }
    __syncthreads();

    // Tail split: waves 0-3: B = gated@Wb + bb (K=256); waves 4-7: C = x@Wc + bc (K=128)
    if (wave < 4) {
        const short* Wbs = (const short*)(ws + OFF_WBS);
        floatx4 accB = {};
#pragma unroll
        for (int ks = 0; ks < 8; ks++) {
            bf16x8 a = *(const bf16x8*)&gbf[wave * 16 + m][ks * 32 + quad * 8];
            bf16x8 b = *(const bf16x8*)(Wbs + (size_t)(ks * 64 + lane) * 8);
            accB = __builtin_amdgcn_mfma_f32_16x16x32_bf16(a, b, accB, 0, 0, 0);
        }
        float bbv = bb[m];
#pragma unroll
        for (int r = 0; r < 4; r++) {
            int row = r0 + wave * 16 + quad * 4 + r;
            Bm[(size_t)row * 16 + m] = accB[r] + bbv;
        }
    } else {
        const short* Wcs = (const short*)(ws + OFF_WCS);
        const int mt = wave - 4;
        floatx4 accC = {};
#pragma unroll
        for (int ks = 0; ks < 4; ks++) {
            bf16x8 a = *(const bf16x8*)&xbf[mt * 16 + m][ks * 32 + quad * 8];
            bf16x8 b = *(const bf16x8*)(Wcs + (size_t)(ks * 64 + lane) * 8);
            accC = __builtin_amdgcn_mfma_f32_16x16x32_bf16(a, b, accC, 0, 0, 0);
        }
        float bcv = bc[m];
#pragma unroll
        for (int r = 0; r < 4; r++) {
            int row = r0 + mt * 16 + quad * 4 + r;
            Cm[(size_t)row * 16 + m] = accC[r] + bcv;
        }
    }
}

// ---------------- xt1 bodies ----------------
// 512-thread variant (2 nodes/block) for fusion into k1's launch
__device__ __forceinline__ void xt1_body512(const float* __restrict__ gx,
                                            const float* __restrict__ W1,
                                            const float* __restrict__ a1,
                                            float* __restrict__ gat, int bid) {
    const int tid = threadIdx.x;
    const int nn = tid >> 8, h = (tid >> 6) & 3, o = tid & 63;
    const int n = bid * 2 + nn;
    float acc = 0.f;
    for (int f = 0; f < 128; f++)
        acc += gx[n * 128 + f] * W1[(h * 128 + f) * 64 + o];
    gat[GXT1 + ((size_t)h * 2048 + n) * 64 + o] = acc;
    float es = acc * a1[h * 128 + o];
    float ed = acc * a1[h * 128 + 64 + o];
#pragma unroll
    for (int off = 32; off > 0; off >>= 1) {
        es += __shfl_down(es, off);
        ed += __shfl_down(ed, off);
    }
    if (o == 0) { gat[GES1 + h * 2048 + n] = es; gat[GED1 + h * 2048 + n] = ed; }
}

// 256-thread variant (1 node/block) for the fallback path
__device__ __forceinline__ void xt1_body(const float* __restrict__ gx,
                                         const float* __restrict__ W1,
                                         const float* __restrict__ a1,
                                         float* __restrict__ gat, int n) {
    const int tid = threadIdx.x;
    const int h = tid >> 6, o = tid & 63;
    float acc = 0.f;
    for (int f = 0; f < 128; f++)
        acc += gx[n * 128 + f] * W1[(h * 128 + f) * 64 + o];
    gat[GXT1 + ((size_t)h * 2048 + n) * 64 + o] = acc;
    float es = acc * a1[h * 128 + o];
    float ed = acc * a1[h * 128 + 64 + o];
#pragma unroll
    for (int off = 32; off > 0; off >>= 1) {
        es += __shfl_down(es, off);
        ed += __shfl_down(ed, off);
    }
    if (o == 0) { gat[GES1 + h * 2048 + n] = es; gat[GED1 + h * 2048 + n] = ed; }
}

// ---------------- K1 standalone (fallback) ----------------
__global__ __launch_bounds__(512, 4) void k1_mfma(
    const float* __restrict__ temporal, const float* __restrict__ pos,
    const float* __restrict__ bi, const float* __restrict__ bg,
    const float* __restrict__ bb, const float* __restrict__ bc,
    const float* __restrict__ ws, float* __restrict__ Bm, float* __restrict__ Cm) {
    __shared__ short xbf[64][136];
    __shared__ short gbf[64][264];
    k1_body(temporal, pos, bi, bg, bb, bc, ws, Bm, Cm, xbf, gbf, blockIdx.x);
}

// ---------------- K1X: k1 + independent xt1 blocks (big_ws only) ----------------
// blocks [0,3200): k1 rows; blocks [3200,4224): xt1 (2 nodes each).
// xt1 is GEMV work that fills k1's idle issue slots (k1: 15% MFMA, 29% VALU).
__global__ __launch_bounds__(512, 4) void k1x_fused(
    const float* __restrict__ temporal, const float* __restrict__ pos,
    const float* __restrict__ bi, const float* __restrict__ bg,
    const float* __restrict__ bb, const float* __restrict__ bc,
    const float* __restrict__ ws, float* __restrict__ Bm, float* __restrict__ Cm,
    const float* __restrict__ gx, const float* __restrict__ W1,
    const float* __restrict__ a1, float* __restrict__ gat) {
    __shared__ short xbf[64][136];
    __shared__ short gbf[64][264];
    if (blockIdx.x < ROWS / 64)
        k1_body(temporal, pos, bi, bg, bb, bc, ws, Bm, Cm, xbf, gbf, blockIdx.x);
    else
        xt1_body512(gx, W1, a1, gat, blockIdx.x - ROWS / 64);
}

// ---------------- scan body (2 nodes / 256-thr block) ----------------
struct __align__(16) ScanSmem { float sb[2][1600]; float sc[2][1600]; };

__device__ __forceinline__ void scan_body(const float* __restrict__ ws,
                                          float* __restrict__ out,
                                          ScanSmem& sm, int bid) {
    const int tid = threadIdx.x;
    const int sub = tid >> 7, t = tid & 127;
    const int n = bid * 2 + sub;
    float* sbp = sm.sb[sub];
    float* scp = sm.sc[sub];
    const float4* Bm4 = (const float4*)(ws + OFF_BM + (size_t)n * 1600);
    const float4* Cm4 = (const float4*)(ws + OFF_CM + (size_t)n * 1600);
#pragma unroll
    for (int i = 0; i < 4; i++) {
        int idx = i * 128 + t;
        if (idx < 400) {
            ((float4*)sbp)[idx] = Bm4[idx];
            ((float4*)scp)[idx] = Cm4[idx];
        }
    }
    float w[16];
#pragma unroll
    for (int s = 0; s < 16; s++) w[s] = ws[OFF_WCOMB + s * 128 + t];
    const float bcb = ws[OFF_BCOMB + t];
    __syncthreads();
    if (t < 16) {
        const int s = t;
        const float As = ws[OFF_AEXP + s];
        float h = 0.f;
#pragma unroll
        for (int lc = 0; lc < 5; lc++) {
            float lb[20], lv[20];
#pragma unroll
            for (int q = 0; q < 20; q++) {
                lb[q] = sbp[(lc * 20 + q) * 16 + s];
                lv[q] = scp[(lc * 20 + q) * 16 + s];
            }
#pragma unroll
            for (int q = 0; q < 20; q++) {
                h = fmaf(As, h, lb[q]);
                sbp[(lc * 20 + q) * 16 + s] = h * lv[q];   // ys in-place
            }
        }
    }
    __syncthreads();
    float* op = out + (size_t)n * L_SEQ * 128 + t;
#pragma unroll 2
    for (int l = 0; l < L_SEQ; l++) {
        const float4 y0 = *(const float4*)(sbp + l * 16 + 0);
        const float4 y1 = *(const float4*)(sbp + l * 16 + 4);
        const float4 y2 = *(const float4*)(sbp + l * 16 + 8);
        const float4 y3 = *(const float4*)(sbp + l * 16 + 12);
        float a0 = fmaf(y0.x, w[0], bcb);
        float a1 = y0.y * w[1];
        float a2 = y0.z * w[2];
        float a3 = y0.w * w[3];
        a0 = fmaf(y1.x, w[4], a0); a1 = fmaf(y1.y, w[5], a1);
        a2 = fmaf(y1.z, w[6], a2); a3 = fmaf(y1.w, w[7], a3);
        a0 = fmaf(y2.x, w[8], a0); a1 = fmaf(y2.y, w[9], a1);
        a2 = fmaf(y2.z, w[10], a2); a3 = fmaf(y2.w, w[11], a3);
        a0 = fmaf(y3.x, w[12], a0); a1 = fmaf(y3.y, w[13], a1);
        a2 = fmaf(y3.z, w[14], a2); a3 = fmaf(y3.w, w[15], a3);
        op[(size_t)l * 128] = (a0 + a1) + (a2 + a3);
    }
}

// ---------------- att1 body (1 node / 256-thr block) ----------------
struct Att1Smem {
    int list[192]; int seg[4][64]; int scnt[4];
    float sh1[256]; float sred[4][64];
};

__device__ __forceinline__ void att1_body(const float* __restrict__ adj,
                                          const float* __restrict__ W2,
                                          const float* __restrict__ a2,
                                          float* __restrict__ gat,
                                          Att1Smem& sm, int n) {
    const int tid = threadIdx.x;
    const int h = tid >> 6, o = tid & 63;
    // ballot-ordered neighbor scan: wave h covers j in [512h, 512h+512)
    {
        int c = 0;
#pragma unroll
        for (int ch = 0; ch < 8; ch++) {
            int j = h * 512 + ch * 64 + o;
            unsigned long long mask = __ballot(adj[(size_t)n * 2048 + j] > 0.f);
            int pos = c + __popcll(mask & ((1ull << o) - 1ull));
            if ((mask >> o) & 1ull) { if (pos < 64) sm.seg[h][pos] = j; }
            c += (int)__popcll(mask);
        }
        if (o == 0) sm.scnt[h] = (c < 64) ? c : 64;
    }
    __syncthreads();
    const int c0 = sm.scnt[0], c1 = sm.scnt[1], c2 = sm.scnt[2], c3 = sm.scnt[3];
    const int offw = (h > 0 ? c0 : 0) + (h > 1 ? c1 : 0) + (h > 2 ? c2 : 0);
    const int cnt = c0 + c1 + c2 + c3;
    if (o < sm.scnt[h]) sm.list[offw + o] = sm.seg[h][o];
    __syncthreads();
    // persist CSR for k7
    {
        int* gcnt  = (int*)(gat + GCNT);
        int* glist = (int*)(gat + GLIST);
        if (tid == 0) gcnt[n] = (cnt < 128) ? cnt : 128;
        if (tid < cnt && tid < 128) glist[(size_t)n * 128 + tid] = sm.list[tid];
    }
    // layer-1 attention
    {
        const float  es = gat[GES1 + h * 2048 + n];
        const float* ed = gat + GED1 + h * 2048;
        const float* xt = gat + GXT1 + (size_t)h * 2048 * 64;
        float num = 0.f, den = 0.f;
        for (int ii = 0; ii < cnt; ii++) {
            int j = sm.list[ii];
            float e = es + ed[j];
            e = (e > 0.f) ? e : 0.2f * e;
            float wgt = expf(e);
            den += wgt;
            num += wgt * xt[(size_t)j * 64 + o];
        }
        float v = num / den;
        sm.sh1[h * 64 + o] = v > 0.f ? v : 0.f;
    }
    __syncthreads();
    {
        float part = 0.f;
        const int f0 = h * 64;
#pragma unroll 8
        for (int f = 0; f < 64; f++)
            part += sm.sh1[f0 + f] * W2[(f0 + f) * 64 + o];
        sm.sred[h][o] = part;
    }
    __syncthreads();
    if (tid < 64) {
        float xt2v = sm.sred[0][tid] + sm.sred[1][tid] + sm.sred[2][tid] + sm.sred[3][tid];
        gat[GXT2 + (size_t)n * 64 + tid] = xt2v;
        float es = xt2v * a2[tid];
        float ed = xt2v * a2[64 + tid];
#pragma unroll
        for (int off = 32; off > 0; off >>= 1) {
            es += __shfl_down(es, off);
            ed += __shfl_down(ed, off);
        }
        if (tid == 0) { gat[GES2 + n] = es; gat[GED2 + n] = ed; }
    }
}

// ---------------- standalone kernels (fallback path) ----------------
__global__ __launch_bounds__(256) void k2_scan(const float* __restrict__ ws,
                                               float* __restrict__ out) {
    __shared__ ScanSmem sm;
    scan_body(ws, out, sm, blockIdx.x);
}

__global__ __launch_bounds__(256) void k4_xt1(const float* __restrict__ gx,
                                              const float* __restrict__ W1,
                                              const float* __restrict__ a1,
                                              float* __restrict__ gat) {
    xt1_body(gx, W1, a1, gat, blockIdx.x);
}

__global__ __launch_bounds__(256) void k56_att1(const float* __restrict__ adj,
                                                const float* __restrict__ W2,
                                                const float* __restrict__ a2,
                                                float* __restrict__ gat) {
    __shared__ Att1Smem sm;
    att1_body(adj, W2, a2, gat, sm, blockIdx.x);
}

// ---------------- kSA: scan + att1 fused (independent work; big_ws only) ----------------
// blocks [0,1024): scan (2 nodes each); blocks [1024,3072): att1 (1 node each)
union KSASmem { ScanSmem s; Att1Smem a; };

__global__ __launch_bounds__(256) void kSA_fused(
    const float* __restrict__ ws, float* __restrict__ out,
    const float* __restrict__ adj, const float* __restrict__ W2,
    const float* __restrict__ a2, float* __restrict__ gat) {
    __shared__ KSASmem sm;
    if (blockIdx.x < N_NODES / 2) scan_body(ws, out, sm.s, blockIdx.x);
    else                          att1_body(adj, W2, a2, gat, sm.a, blockIdx.x - N_NODES / 2);
}

// ---------------- K7: layer-2 attention -> gat out (consumes CSR) ----------------
__global__ __launch_bounds__(256) void k7_att2(const float* __restrict__ gat,
                                               float* __restrict__ gout) {
    __shared__ int list[128];
    __shared__ float snum[4][64];
    __shared__ float sden[4];
    const int n = blockIdx.x, tid = threadIdx.x;
    const int g = tid >> 6, o = tid & 63;
    const int* gcnt  = (const int*)(gat + GCNT);
    const int* glist = (const int*)(gat + GLIST);
    const int mm = gcnt[n];
    if (tid < mm) list[tid] = glist[(size_t)n * 128 + tid];
    __syncthreads();
    const float es = gat[GES2 + n];
    float num = 0.f, den = 0.f;
    for (int ii = g; ii < mm; ii += 4) {
        int j = list[ii];
        float e = es + gat[GED2 + j];
        e = (e > 0.f) ? e : 0.2f * e;
        float wgt = expf(e);
        den += wgt;
        num += wgt * gat[GXT2 + (size_t)j * 64 + o];
    }
    snum[g][o] = num;
    if (o == 0) sden[g] = den;
    __syncthreads();
    if (tid < 64) {
        float nt = snum[0][tid] + snum[1][tid] + snum[2][tid] + snum[3][tid];
        float dt = sden[0] + sden[1] + sden[2] + sden[3];
        gout[(size_t)n * 64 + tid] = nt / dt;
    }
}

extern "C" void kernel_launch(void* const* d_in, const int* in_sizes, int n_in,
                              void* d_out, int out_size, void* d_ws, size_t ws_size,
                              hipStream_t stream) {
    const float* temporal = (const float*)d_in[0];
    const float* graph_x  = (const float*)d_in[1];
    const float* adj      = (const float*)d_in[2];
    const float* pos      = (const float*)d_in[3];
    const float* Wi  = (const float*)d_in[4];
    const float* bi  = (const float*)d_in[5];
    const float* Wg  = (const float*)d_in[6];
    const float* bg  = (const float*)d_in[7];
    const float* A_log = (const float*)d_in[8];
    const float* Wb  = (const float*)d_in[9];
    const float* bb  = (const float*)d_in[10];
    const float* Wc  = (const float*)d_in[11];
    const float* bc  = (const float*)d_in[12];
    const float* Wo  = (const float*)d_in[13];
    const float* bo  = (const float*)d_in[14];
    const float* Wfc = (const float*)d_in[15];
    const float* bfc = (const float*)d_in[16];
    const float* W1  = (const float*)d_in[17];
    const float* a1  = (const float*)d_in[18];
    const float* W2  = (const float*)d_in[19];
    const float* a2  = (const float*)d_in[20];

    float* ws = (float*)d_ws;
    float* out_mamba = (float*)d_out;
    float* out_gat   = out_mamba + (size_t)ROWS * 128;

    const bool big_ws = ws_size >= (OFF_GAT_BIG + GAT_TOTAL) * sizeof(float);
    float* gat = big_ws ? (ws + OFF_GAT_BIG) : (ws + OFF_BM);   // alias BM if tight

    kA_prep<<<289, 256, 0, stream>>>(Wo, bo, Wfc, bfc, A_log, Wi, Wg, Wb, Wc, ws);
    if (big_ws) {
        // 4 launches: k1+xt1 overlapped, scan+att1 overlapped
        k1x_fused<<<ROWS / 64 + N_NODES / 2, 512, 0, stream>>>(
            temporal, pos, bi, bg, bb, bc, ws, ws + OFF_BM, ws + OFF_CM,
            graph_x, W1, a1, gat);
        kSA_fused<<<N_NODES / 2 + N_NODES, 256, 0, stream>>>(
            ws, out_mamba, adj, W2, a2, gat);
        k7_att2<<<N_NODES, 256, 0, stream>>>(gat, out_gat);
    } else {
        // proven round-5 sequential path (gat aliases BM; xt1 must follow scan)
        k1_mfma<<<ROWS / 64, 512, 0, stream>>>(temporal, pos, bi, bg, bb, bc, ws,
                                               ws + OFF_BM, ws + OFF_CM);
        k2_scan<<<N_NODES / 2, 256, 0, stream>>>(ws, out_mamba);
        k4_xt1<<<N_NODES, 256, 0, stream>>>(graph_x, W1, a1, gat);
        k56_att1<<<N_NODES, 256, 0, stream>>>(adj, W2, a2, gat);
        k7_att2<<<N_NODES, 256, 0, stream>>>(gat, out_gat);
    }
}